// Round 13
// baseline (33177.643 us; speedup 1.0000x reference)
//
#include <hip/hip_runtime.h>
#include <cmath>

#define TDEC 250
#define EPS_A 1e-6f

// ---------------- block groups ----------------
#define NB_GRU1 64   // 32 blocks: 4bg x 8jg
#define NB_GRU2 96   // 32
#define NB_PROJ 128  // 16: 4bg x 4jg
#define NB_GIC  144  // 64: 4bg x 16jg
#define NB_GA   208  // 16: 4bg x 4jg
#define NBLK    224

// ---------------- ws float offsets (flags in words 0..8191) ----------------
// MEGA flag words: 0=ctx, 1=hatt, 2=x. helpers: word 0.
#define B_CTX(p)  (8192   + (p)*49152)   // [64][768]
#define B_HATT(p) (106496 + (p)*16384)   // [64][256]
#define B_H1(p)   (139264 + (p)*16384)
#define B_H2(p)   (172032 + (p)*16384)
#define B_X(p)    (204800 + (p)*16384)
#define B_X2(p)   (237568 + (p)*16384)
#define B_X3(p)   (270336 + (p)*16384)
#define B_FR(p)   (303104 + (p)*25600)   // [64][400]
#define B_GIC(p)  (354304 + (p)*49152)   // [64][768]
#define B_GH(p)   (452608 + (p)*49152)   // [64][768]
#define ZERO_END  550912
#define CVT_OFF   550912                 // bf16 weight region (u16)

// bf16 weight offsets (u16 units)
#define OP1   0u        // p1w  [256][416] (rows padded 400->416)
#define OP2   106496u   // p2w  [128][256]
#define OAWI  139264u   // awi  [768][896]
#define OAWH  827392u   // awh  [768][256]
#define ODW   1024000u  // dWw  [128][256]
#define OLW   1056768u  // lw   [256][1024]
#define OG1I  1318912u  // g1wi [768][256]
#define OG1H  1515520u
#define OG2I  1712128u
#define OG2H  1908736u
#define OPR   2105344u  // prw  [400][256]

struct Prior { float v[11]; };

struct KArgs {
  const float *enc;
  const float *p1w,*p1b,*p2w,*p2b;
  const float *awi,*abi,*awh,*abh;
  const float *dWw,*dWb,*dVw,*dFw,*dUw,*dTw,*dTb,*dvw;
  const float *lw,*lb;
  const float *g1wi,*g1bi,*g1wh,*g1bh;
  const float *g2wi,*g2bi,*g2wh,*g2bh;
  const float *prw,*prb;
  float* ws; float* dout;
  Prior pr;
};

__device__ __forceinline__ float gld(const float* p) {
  return __uint_as_float(__hip_atomic_load((const unsigned*)p, __ATOMIC_RELAXED, __HIP_MEMORY_SCOPE_AGENT));
}
__device__ __forceinline__ void gst(float* p, float v) {
  __hip_atomic_store((unsigned*)p, __float_as_uint(v), __ATOMIC_RELAXED, __HIP_MEMORY_SCOPE_AGENT);
}
__device__ __forceinline__ float sigm(float x) { return 1.f / (1.f + expf(-x)); }

// bf16-pair dot: one uint4 = 8 bf16 weights vs 8 fp32 activations (two float4)
__device__ __forceinline__ float dot8(uint4 w, float4 x0, float4 x1) {
  float a;
  a = __uint_as_float(w.x << 16) * x0.x;
  a = fmaf(__uint_as_float(w.x & 0xffff0000u), x0.y, a);
  a = fmaf(__uint_as_float(w.y << 16),         x0.z, a);
  a = fmaf(__uint_as_float(w.y & 0xffff0000u), x0.w, a);
  a = fmaf(__uint_as_float(w.z << 16),         x1.x, a);
  a = fmaf(__uint_as_float(w.z & 0xffff0000u), x1.y, a);
  a = fmaf(__uint_as_float(w.w << 16),         x1.z, a);
  a = fmaf(__uint_as_float(w.w & 0xffff0000u), x1.w, a);
  return a;
}

__global__ __launch_bounds__(256) void k_init(float* ws) {
  int idx = blockIdx.x * 256 + threadIdx.x;
  for (int i = idx; i < ZERO_END; i += gridDim.x * 256) ws[i] = 0.f;
}

// ---------------- fp32 -> bf16 (RTNE) weight conversion ----------------
struct CvtSeg { const float* src; unsigned dst; unsigned n; };
struct CvtArgs { CvtSeg s[11]; };
__global__ __launch_bounds__(256) void k_cvt(CvtArgs c, unsigned short* wb) {
  // seg 0: p1w with row padding 400 -> 416
  for (unsigned i = blockIdx.x * 256 + threadIdx.x; i < 256u * 416u; i += gridDim.x * 256) {
    unsigned row = i / 416u, col = i - row * 416u;
    unsigned short v = 0;
    if (col < 400u) {
      unsigned u = __float_as_uint(c.s[0].src[row * 400u + col]);
      v = (unsigned short)((u + 0x7fffu + ((u >> 16) & 1u)) >> 16);
    }
    wb[OP1 + i] = v;
  }
  for (int seg = 1; seg < 11; ++seg) {
    const float* s = c.s[seg].src;
    unsigned short* d = wb + c.s[seg].dst;
    unsigned n = c.s[seg].n;
    for (unsigned i = blockIdx.x * 256 + threadIdx.x; i < n; i += gridDim.x * 256) {
      unsigned u = __float_as_uint(s[i]);
      d[i] = (unsigned short)((u + 0x7fffu + ((u >> 16) & 1u)) >> 16);
    }
  }
}

__device__ __forceinline__ void postw(unsigned* fl, int word, unsigned v) {
  asm volatile("s_waitcnt vmcnt(0)" ::: "memory");
  __syncthreads();
  if (threadIdx.x == 0)
    __hip_atomic_store(&fl[blockIdx.x * 32 + word], v, __ATOMIC_RELAXED, __HIP_MEMORY_SCOPE_AGENT);
}
template <int SLP>
__device__ __forceinline__ void pollge(unsigned* fl, int line, int word, unsigned v) {
  while (__hip_atomic_load(&fl[line * 32 + word], __ATOMIC_RELAXED, __HIP_MEMORY_SCOPE_AGENT) < v)
    __builtin_amdgcn_s_sleep(SLP);
}

// ---------------- GRU block group (32 blocks: 4bg x 8jg, 16b x 32j) -------------
__device__ void gru_block(float* sm, unsigned* fl, float* ws, const unsigned short* wb,
                          int bg, int jg, int selfL0, int prodL0, int prodN, int prodWord,
                          unsigned OWh, unsigned OWi, const float* bi, const float* bh,
                          int offH0, int offXin0, int offXout0) {
  const int tid = threadIdx.x;
  const int B = bg * 16, J0 = jg * 32;
  float* hp   = sm;          // [16][260]
  float* gh1l = sm + 4160;   // [96][16]
  float* xs   = sm + 5696;   // [16][260]
  float* gil  = sm + 9856;   // [96][16]
  for (int t = 0; t < TDEC; ++t) {
    const int p = t & 1;
    // shadow: gh = Wh @ h(t-1)
    if (tid < 8) pollge<4>(fl, selfL0 + tid, 0, (unsigned)t);
    __syncthreads();
    for (int idx = tid; idx < 4096; idx += 1024) {
      int bb = idx >> 8, k = idx & 255;
      hp[bb * 260 + k] = gld(ws + offH0 + (p ^ 1) * 16384 + (B + bb) * 256 + k);
    }
    __syncthreads();
#pragma unroll
    for (int pass = 0; pass < 2; ++pass) {
      if (tid < 768) {
        int lr = pass * 48 + (tid >> 4), bb = tid & 15;
        int wrow = (lr >> 5) * 256 + J0 + (lr & 31);
        const uint4* wr = (const uint4*)(wb + OWh + (size_t)wrow * 256);
        const float4* xr = (const float4*)(hp + bb * 260);
        float a = 0.f;
#pragma unroll 16
        for (int k4 = 0; k4 < 32; ++k4) a += dot8(wr[k4], xr[2*k4], xr[2*k4+1]);
        gh1l[lr * 16 + bb] = a + bh[wrow];
      }
    }
    // main: wait x
    if (tid < prodN) pollge<1>(fl, prodL0 + tid, prodWord, (unsigned)(t + 1));
    __syncthreads();
    for (int idx = tid; idx < 4096; idx += 1024) {
      int bb = idx >> 8, k = idx & 255;
      xs[bb * 260 + k] = gld(ws + offXin0 + p * 16384 + (B + bb) * 256 + k);
    }
    __syncthreads();
#pragma unroll
    for (int pass = 0; pass < 2; ++pass) {
      if (tid < 768) {
        int lr = pass * 48 + (tid >> 4), bb = tid & 15;
        int wrow = (lr >> 5) * 256 + J0 + (lr & 31);
        const uint4* wr = (const uint4*)(wb + OWi + (size_t)wrow * 256);
        const float4* xr = (const float4*)(xs + bb * 260);
        float a = 0.f;
#pragma unroll 16
        for (int k4 = 0; k4 < 32; ++k4) a += dot8(wr[k4], xr[2*k4], xr[2*k4+1]);
        gil[lr * 16 + bb] = a + bi[wrow];
      }
    }
    __syncthreads();
    if (tid < 512) {
      int lj = tid >> 4, bb = tid & 15;
      float r = sigm(gil[lj * 16 + bb] + gh1l[lj * 16 + bb]);
      float z = sigm(gil[(32 + lj) * 16 + bb] + gh1l[(32 + lj) * 16 + bb]);
      float n = tanhf(gil[(64 + lj) * 16 + bb] + r * gh1l[(64 + lj) * 16 + bb]);
      float hprev = hp[bb * 260 + J0 + lj];
      float hnew = (1.f - z) * n + z * hprev;
      gst(ws + offH0 + p * 16384 + (B + bb) * 256 + J0 + lj, hnew);
      gst(ws + offXout0 + p * 16384 + (B + bb) * 256 + J0 + lj, xs[bb * 260 + J0 + lj] + hnew);
    }
    postw(fl, 0, (unsigned)(t + 1));
  }
}

// ---------------- the persistent decoder ----------------
__global__ __launch_bounds__(1024, 1) void k_decode(KArgs A) {
  __shared__ __align__(16) float sm[31960];
  float* ws = A.ws;
  unsigned* fl = (unsigned*)ws;
  const unsigned short* wb = (const unsigned short*)(ws + CVT_OFF);
  const int blk = blockIdx.x;
  const int tid = threadIdx.x;

  if (blk < 64) {
    // ========== MEGA: per-b. prenet + att-GRU + dW/dV + convs + softmax + ctx + lw ==========
    const int b = blk, bg = b >> 4;
    float* alpha = sm;            // 512
    float* hattl = sm + 512;      // 256
    float* sal   = sm + 768;      // 544
    float* fr    = sm + 1312;     // 416 (400 + 16 zero pad)
    float* h1s   = sm + 1728;     // 256
    float* pre   = sm + 1984;     // 128
    float* sgi   = sm + 2112;     // 768
    float* sgh   = sm + 2880;     // 768
    float* t1    = sm + 3648;     // 128
    float* Gl    = sm + 3776;     // 176
    float* sdF   = sm + 3952;     // 176
    float* sdU   = sm + 4128;     // 1024
    float* sdT   = sm + 5152;     // 1024
    float* sdtb  = sm + 6176;     // 128
    float* sdv   = sm + 6304;     // 128
    float* es    = sm + 6432;     // 1024
    float* e     = sm + 7456;     // 512
    float* red   = sm + 7968;     // 16
    int*   wc    = (int*)(sm + 7984); // 8
    float* lv    = sm + 7992;     // 512
    short* li    = (short*)(sm + 8504); // 512 shorts
    float* ctxl  = sm + 8760;     // 768
    float* sdV   = sm + 9528;     // 168x132 = 22176

    if (tid < 512) alpha[tid] = (tid == 0) ? 1.f : 0.f;
    if (tid < 256) hattl[tid] = 0.f;
    if (tid < 176) sdF[tid] = (tid < 168) ? A.dFw[tid] : 0.f;
    if (tid >= 400 && tid < 416) fr[tid] = 0.f;   // pad stays zero
    sdU[tid] = A.dUw[tid];
    sdT[tid] = A.dTw[tid];
    if (tid < 128) { sdtb[tid] = A.dTb[tid]; sdv[tid] = A.dvw[tid]; }
    for (int i = tid; i < 21504; i += 1024) sdV[(i >> 7) * 132 + (i & 127)] = A.dVw[i];
    __syncthreads();

    for (int t = 0; t < TDEC; ++t) {
      const int p = t & 1;
      // S0: wait frame(t) + alpha->sal
      if (tid < 544) { int sg = tid - 10; sal[tid] = (sg >= 0 && sg < 512) ? alpha[sg] : 0.f; }
      else if (tid >= 544 && tid < 548) pollge<1>(fl, NB_PROJ + bg * 4 + (tid - 544), 0, (unsigned)t);
      __syncthreads();
      if (tid < 400) fr[tid] = gld(ws + B_FR(p) + b * 400 + tid);
      __syncthreads();
      // S1: prenet L1 (256 j x 4 parts, constant 13-iter unrolled)
      {
        int j = tid >> 2, part = tid & 3;
        const uint4* wr = (const uint4*)(wb + OP1 + (size_t)j * 416) + part * 13;
        const float4* xr = (const float4*)fr + part * 26;
        float a = 0.f;
#pragma unroll
        for (int k4 = 0; k4 < 13; ++k4) a += dot8(wr[k4], xr[2*k4], xr[2*k4+1]);
        a += __shfl_xor(a, 1); a += __shfl_xor(a, 2);
        if (part == 0) h1s[j] = fmaxf(a + A.p1b[j], 0.f);
      }
      __syncthreads();
      // S2: prenet L2 (128 j x 8 parts, constant 4-iter)
      {
        int j = tid >> 3, part = tid & 7;
        const uint4* wr = (const uint4*)(wb + OP2 + (size_t)j * 256) + part * 4;
        const float4* xr = (const float4*)h1s + part * 8;
        float a = 0.f;
#pragma unroll
        for (int k4 = 0; k4 < 4; ++k4) a += dot8(wr[k4], xr[2*k4], xr[2*k4+1]);
        a += __shfl_xor(a, 1); a += __shfl_xor(a, 2); a += __shfl_xor(a, 4);
        if (part == 0) pre[j] = fmaxf(a + A.p2b[j], 0.f);
      }
      __syncthreads();
      // S3: gip (local awi pre-slice, bf16) || poll GIC + GA
      float gipre = 0.f;
      if (tid < 768) {
        const uint4* wr = (const uint4*)(wb + OAWI + (size_t)tid * 896 + 768);
        const float4* xr = (const float4*)pre;
        float a = 0.f;
#pragma unroll
        for (int k4 = 0; k4 < 16; ++k4) a += dot8(wr[k4], xr[2*k4], xr[2*k4+1]);
        gipre = a;
      } else if (tid < 784) {
        pollge<1>(fl, NB_GIC + bg * 16 + (tid - 768), 0, (unsigned)(t + 1));
      } else if (tid < 788) {
        pollge<1>(fl, NB_GA + bg * 4 + (tid - 784), 0, (unsigned)(t + 1));
      }
      __syncthreads();
      // S4: gate pre-activations
      if (tid < 768) {
        sgi[tid] = gipre + gld(ws + B_GIC(p) + b * 768 + tid) + A.abi[tid];
        sgh[tid] = gld(ws + B_GH(p) + b * 768 + tid) + A.abh[tid];
      }
      __syncthreads();
      // S5: att-GRU combine -> hatt
      if (tid < 256) {
        float r = sigm(sgi[tid] + sgh[tid]);
        float z = sigm(sgi[256 + tid] + sgh[256 + tid]);
        float n = tanhf(sgi[512 + tid] + r * sgh[512 + tid]);
        float hnew = (1.f - z) * n + z * hattl[tid];
        hattl[tid] = hnew;
        gst(ws + B_HATT(p) + b * 256 + tid, hnew);
      }
      postw(fl, 1, (unsigned)(t + 1));
      // S6: t1 = tanh(dW @ hatt + dWb) (constant 4-iter)
      {
        int j = tid >> 3, part = tid & 7;
        const uint4* wr = (const uint4*)(wb + ODW + (size_t)j * 256) + part * 4;
        const float4* xr = (const float4*)hattl + part * 8;
        float a = 0.f;
#pragma unroll
        for (int k4 = 0; k4 < 4; ++k4) a += dot8(wr[k4], xr[2*k4], xr[2*k4+1]);
        a += __shfl_xor(a, 1); a += __shfl_xor(a, 2); a += __shfl_xor(a, 4);
        if (part == 0) t1[j] = tanhf(a + A.dWb[j]);
      }
      __syncthreads();
      // S7: G = dV @ t1 (dV LDS-cached fp32)
      if (tid < 168) {
        const float4* wr = (const float4*)(sdV + tid * 132);
        const float4* xr = (const float4*)t1;
        float a = 0.f;
#pragma unroll 8
        for (int k4 = 0; k4 < 32; ++k4) {
          float4 av = xr[k4], wv = wr[k4];
          a = fmaf(av.x,wv.x, fmaf(av.y,wv.y, fmaf(av.z,wv.z, fmaf(av.w,wv.w, a))));
        }
        Gl[tid] = a;
      }
      __syncthreads();
      // S8: static+dynamic conv fused with energy MLP
      {
        int sl = tid >> 1, half = tid & 1;
        float f0[8], g0[8];
#pragma unroll
        for (int q = 0; q < 8; ++q) {
          float fa = 0.f, ga = 0.f;
#pragma unroll
          for (int k = 0; k < 21; ++k) {
            float a = sal[sl + k];
            fa = fmaf(sdF[q * 21 + k], a, fa);
            ga = fmaf(Gl[q * 21 + k], a, ga);
          }
          f0[q] = fa; g0[q] = ga;
        }
        float acc = 0.f;
        for (int cc = half * 64; cc < half * 64 + 64; ++cc) {
          float a = sdtb[cc];
#pragma unroll
          for (int q = 0; q < 8; ++q)
            a = fmaf(sdU[cc * 8 + q], f0[q], fmaf(sdT[cc * 8 + q], g0[q], a));
          acc = fmaf(sdv[cc], tanhf(a), acc);
        }
        es[sl * 2 + half] = acc;
      }
      __syncthreads();
      // S9a: e = mlp + log(prior)
      if (tid < 512) {
        float pr = 0.f;
#pragma unroll
        for (int k = 0; k < 11; ++k) pr = fmaf(A.pr.v[k], sal[tid + k], pr);
        e[tid] = es[tid * 2] + es[tid * 2 + 1] + logf(fmaxf(pr, 1e-6f));
      }
      __syncthreads();
      // S9b: softmax + compaction + sparse ctx (enc via L2-bypass loads)
      {
        int lane = tid & 63, wv = tid >> 6;
        float e0 = (tid < 512) ? e[tid] : -1e30f;
        float m = e0;
        for (int o = 32; o; o >>= 1) m = fmaxf(m, __shfl_xor(m, o));
        if (lane == 0) red[wv] = m;
        __syncthreads();
        m = red[0];
        for (int w = 1; w < 8; ++w) m = fmaxf(m, red[w]);
        float p0 = (tid < 512) ? expf(e0 - m) : 0.f;
        float s = p0;
        for (int o = 32; o; o >>= 1) s += __shfl_xor(s, o);
        __syncthreads();
        if (lane == 0) red[wv] = s;
        __syncthreads();
        float tot = red[0];
        for (int w = 1; w < 8; ++w) tot += red[w];
        float inv = 1.f / tot;
        float a0 = p0 * inv;
        if (tid < 512) alpha[tid] = a0;
        unsigned long long mk = __ballot(tid < 512 && a0 > EPS_A);
        if (lane == 0 && wv < 8) wc[wv] = (int)__popcll(mk);
        __syncthreads();
        int base = 0;
        for (int w = 0; w < wv && w < 8; ++w) base += wc[w];
        int n = 0;
        for (int w = 0; w < 8; ++w) n += wc[w];
        unsigned long long below = (1ull << lane) - 1ull;
        if (tid < 512 && a0 > EPS_A) {
          int pp = base + (int)__popcll(mk & below);
          li[pp] = (short)tid; lv[pp] = a0;
        }
        __syncthreads();
        const float* encb = A.enc + (size_t)b * 512 * 768;
        if (tid < 768) {
          float acc = 0.f;
          int i = 0;
          for (; i + 4 <= n; i += 4) {
            float v0 = gld(encb + (size_t)li[i] * 768 + tid);
            float v1 = gld(encb + (size_t)li[i+1] * 768 + tid);
            float v2 = gld(encb + (size_t)li[i+2] * 768 + tid);
            float v3 = gld(encb + (size_t)li[i+3] * 768 + tid);
            acc = fmaf(lv[i],v0, fmaf(lv[i+1],v1, fmaf(lv[i+2],v2, fmaf(lv[i+3],v3, acc))));
          }
          for (; i < n; ++i) acc = fmaf(lv[i], gld(encb + (size_t)li[i] * 768 + tid), acc);
          ctxl[tid] = acc;
          gst(ws + B_CTX(p) + b * 768 + tid, acc);
        }
      }
      postw(fl, 0, (unsigned)(t + 1));
      // S10: x = lw @ [ctx; hatt] + lb (constant 32-iter chunks)
      {
        int j = tid >> 2, part = tid & 3;
        const uint4* wr = (const uint4*)(wb + OLW + (size_t)j * 1024) + part * 32;
        const float4* xr = (part < 3) ? ((const float4*)ctxl + part * 64) : (const float4*)hattl;
        float a = 0.f;
#pragma unroll 16
        for (int k4 = 0; k4 < 32; ++k4) a += dot8(wr[k4], xr[2*k4], xr[2*k4+1]);
        a += __shfl_xor(a, 1); a += __shfl_xor(a, 2);
        if (part == 0) gst(ws + B_X(p) + b * 256 + j, a + A.lb[j]);
      }
      postw(fl, 2, (unsigned)(t + 1));
    }
  } else if (blk < NB_GRU2) {
    int rb = blk - NB_GRU1;
    int bg = rb >> 3, jg = rb & 7;
    gru_block(sm, fl, ws, wb, bg, jg, NB_GRU1 + bg * 8, bg * 16, 16, 2,
              OG1H, OG1I, A.g1bi, A.g1bh, B_H1(0), B_X(0), B_X2(0));
  } else if (blk < NB_PROJ) {
    int rb = blk - NB_GRU2;
    int bg = rb >> 3, jg = rb & 7;
    gru_block(sm, fl, ws, wb, bg, jg, NB_GRU2 + bg * 8, NB_GRU1 + bg * 8, 8, 0,
              OG2H, OG2I, A.g2bi, A.g2bh, B_H2(0), B_X2(0), B_X3(0));
  } else if (blk < NB_GIC) {
    // ---- PROJ: frame(t+1) = prw @ x3 + prb; dout row t (bypass stores) ----
    int rb = blk - NB_PROJ, bg = rb >> 2, jg = rb & 3;
    int B = bg * 16, J0 = jg * 100;
    float* xs = sm;   // [16][260]
    for (int t = 0; t < TDEC; ++t) {
      const int p = t & 1;
      if (tid < 8) pollge<1>(fl, NB_GRU2 + bg * 8 + tid, 0, (unsigned)(t + 1));
      __syncthreads();
      for (int idx = tid; idx < 4096; idx += 1024) {
        int bb = idx >> 8, k = idx & 255;
        xs[bb * 260 + k] = gld(ws + B_X3(p) + (B + bb) * 256 + k);
      }
      __syncthreads();
#pragma unroll
      for (int pass = 0; pass < 2; ++pass) {
        int bb = pass * 8 + (tid & 7), lj = tid >> 3;
        if (lj < 100) {
          int row = J0 + lj;
          const uint4* wr = (const uint4*)(wb + OPR + (size_t)row * 256);
          const float4* xr = (const float4*)(xs + bb * 260);
          float a = 0.f;
#pragma unroll 16
          for (int k4 = 0; k4 < 32; ++k4) a += dot8(wr[k4], xr[2*k4], xr[2*k4+1]);
          float v = a + A.prb[row];
          gst(ws + B_FR((t + 1) & 1) + (B + bb) * 400 + row, v);
          gst(A.dout + (size_t)(B + bb) * 100000 + (row / 5) * 1250 + t * 5 + (row % 5), v);
        }
      }
      postw(fl, 0, (unsigned)(t + 1));
    }
  } else if (blk < NB_GA) {
    // ---- GIC: gic(t) = awi[:, :768] @ ctx(t-1)  (shadow) ----
    int rb = blk - NB_GIC, bg = rb >> 4, jg = rb & 15;
    int B = bg * 16, R0 = jg * 48;
    float* cl = sm;  // [16][772]
    for (int t = 0; t < TDEC; ++t) {
      const int p = t & 1;
      if (tid < 16) pollge<4>(fl, bg * 16 + tid, 0, (unsigned)t);
      __syncthreads();
      for (int idx = tid; idx < 12288; idx += 1024) {
        int bb = idx / 768, k = idx - bb * 768;
        cl[bb * 772 + k] = gld(ws + B_CTX(p ^ 1) + (B + bb) * 768 + k);
      }
      __syncthreads();
      if (tid < 768) {
        int rr = tid >> 4, bb = tid & 15;
        int row = R0 + rr;
        const uint4* wr = (const uint4*)(wb + OAWI + (size_t)row * 896);
        const float4* xr = (const float4*)(cl + bb * 772);
        float a = 0.f;
#pragma unroll 16
        for (int k4 = 0; k4 < 96; ++k4) a += dot8(wr[k4], xr[2*k4], xr[2*k4+1]);
        gst(ws + B_GIC(p) + (B + bb) * 768 + row, a);
      }
      postw(fl, 0, (unsigned)(t + 1));
    }
  } else {
    // ---- GA: gh(t) = awh @ hatt(t-1)  (shadow) ----
    int rb = blk - NB_GA, bg = rb >> 2, jg = rb & 3;
    int B = bg * 16, R0 = jg * 192;
    float* hl = sm;  // [16][260]
    for (int t = 0; t < TDEC; ++t) {
      const int p = t & 1;
      if (tid < 16) pollge<4>(fl, bg * 16 + tid, 1, (unsigned)t);
      __syncthreads();
      for (int idx = tid; idx < 4096; idx += 1024) {
        int bb = idx >> 8, k = idx & 255;
        hl[bb * 260 + k] = gld(ws + B_HATT(p ^ 1) + (B + bb) * 256 + k);
      }
      __syncthreads();
#pragma unroll
      for (int pass = 0; pass < 3; ++pass) {
        int rr = pass * 64 + (tid >> 4), bb = tid & 15;
        int row = R0 + rr;
        const uint4* wr = (const uint4*)(wb + OAWH + (size_t)row * 256);
        const float4* xr = (const float4*)(hl + bb * 260);
        float a = 0.f;
#pragma unroll 16
        for (int k4 = 0; k4 < 32; ++k4) a += dot8(wr[k4], xr[2*k4], xr[2*k4+1]);
        gst(ws + B_GH(p) + (B + bb) * 768 + row, a);
      }
      postw(fl, 0, (unsigned)(t + 1));
    }
  }
}

// ---------------- host ----------------
extern "C" void kernel_launch(void* const* d_in, const int* in_sizes, int n_in,
                              void* d_out, int out_size, void* d_ws, size_t ws_size,
                              hipStream_t stream) {
  (void)in_sizes; (void)n_in; (void)out_size; (void)ws_size;
  KArgs A;
  A.enc  = (const float*)d_in[0];
  A.p1w  = (const float*)d_in[1];  A.p1b  = (const float*)d_in[2];
  A.p2w  = (const float*)d_in[3];  A.p2b  = (const float*)d_in[4];
  A.awi  = (const float*)d_in[5];  A.abi  = (const float*)d_in[6];
  A.awh  = (const float*)d_in[7];  A.abh  = (const float*)d_in[8];
  A.dWw  = (const float*)d_in[9];  A.dWb  = (const float*)d_in[10];
  A.dVw  = (const float*)d_in[11]; A.dFw  = (const float*)d_in[12];
  A.dUw  = (const float*)d_in[13]; A.dTw  = (const float*)d_in[14];
  A.dTb  = (const float*)d_in[15]; A.dvw  = (const float*)d_in[16];
  A.lw   = (const float*)d_in[17]; A.lb   = (const float*)d_in[18];
  A.g1wi = (const float*)d_in[19]; A.g1bi = (const float*)d_in[20];
  A.g1wh = (const float*)d_in[21]; A.g1bh = (const float*)d_in[22];
  A.g2wi = (const float*)d_in[23]; A.g2bi = (const float*)d_in[24];
  A.g2wh = (const float*)d_in[25]; A.g2bh = (const float*)d_in[26];
  A.prw  = (const float*)d_in[27]; A.prb  = (const float*)d_in[28];
  A.ws   = (float*)d_ws;
  A.dout = (float*)d_out;

  // beta-binomial prior pmf (n=10, a=0.1, b=0.9), flipped
  {
    double aP = 0.1, bP = 0.9;
    double logB0 = lgamma(aP) + lgamma(bP) - lgamma(aP + bP);
    double pm[11];
    for (int k = 0; k <= 10; ++k) {
      double logC = lgamma(11.0) - lgamma(k + 1.0) - lgamma(11.0 - k);
      double logBt = lgamma(k + aP) + lgamma(10.0 - k + bP) - lgamma(10.0 + aP + bP);
      pm[k] = exp(logC + logBt - logB0);
    }
    for (int k = 0; k < 11; ++k) A.pr.v[k] = (float)pm[10 - k];
  }

  CvtArgs C;
  C.s[0]  = {A.p1w,  OP1,  106496u};   // padded inside k_cvt
  C.s[1]  = {A.p2w,  OP2,  32768u};
  C.s[2]  = {A.awi,  OAWI, 688128u};
  C.s[3]  = {A.awh,  OAWH, 196608u};
  C.s[4]  = {A.dWw,  ODW,  32768u};
  C.s[5]  = {A.lw,   OLW,  262144u};
  C.s[6]  = {A.g1wi, OG1I, 196608u};
  C.s[7]  = {A.g1wh, OG1H, 196608u};
  C.s[8]  = {A.g2wi, OG2I, 196608u};
  C.s[9]  = {A.g2wh, OG2H, 196608u};
  C.s[10] = {A.prw,  OPR,  102400u};

  k_init<<<256, 256, 0, stream>>>((float*)d_ws);
  k_cvt<<<256, 256, 0, stream>>>(C, (unsigned short*)((float*)d_ws + CVT_OFF));
  k_decode<<<NBLK, 1024, 0, stream>>>(A);
}